// Round 1
// baseline (22416.843 us; speedup 1.0000x reference)
//
#include <hip/hip_runtime.h>
#include <hip/hip_bf16.h>
#include <cstdint>

#define NB 64      // batch
#define SL 1024    // seq len
#define ED 128     // embed
#define HD 256     // hidden
#define GG 1024    // 4*H
#define NT 35      // tags
#define TSTART 33

typedef unsigned int uint;

__device__ __forceinline__ float sigf(float x){ return 1.f/(1.f+expf(-x)); }

__device__ __forceinline__ void unpack8(uint4 w, float* f){
  f[0]=__uint_as_float(w.x<<16); f[1]=__uint_as_float(w.x&0xffff0000u);
  f[2]=__uint_as_float(w.y<<16); f[3]=__uint_as_float(w.y&0xffff0000u);
  f[4]=__uint_as_float(w.z<<16); f[5]=__uint_as_float(w.z&0xffff0000u);
  f[6]=__uint_as_float(w.w<<16); f[7]=__uint_as_float(w.w&0xffff0000u);
}

// K0: convert weights to bf16 (RNE), sum biases.
// wbf layout: [wihf 131072][whhf 262144][wihb 131072][whhb 262144]
__global__ void conv_kernel(const float* __restrict__ wihf, const float* __restrict__ whhf,
                            const float* __restrict__ wihb, const float* __restrict__ whhb,
                            const float* __restrict__ bihf, const float* __restrict__ bhhf,
                            const float* __restrict__ bihb, const float* __restrict__ bhhb,
                            __hip_bfloat16* __restrict__ wbf, float* __restrict__ bias){
  int i = blockIdx.x*blockDim.x + threadIdx.x;
  if (i < 786432){
    float v;
    if      (i < 131072) v = wihf[i];
    else if (i < 393216) v = whhf[i-131072];
    else if (i < 524288) v = wihb[i-393216];
    else                 v = whhb[i-524288];
    wbf[i] = __float2bfloat16(v);
  }
  if (i < 1024)      bias[i] = bihf[i] + bhhf[i];
  else if (i < 2048) bias[i] = bihb[i-1024] + bhhb[i-1024];
}

// K1: fused embed-gather + input projection + LSTM recurrence.
// grid (32 chunks of 2 batches, 2 dirs), block 1024 (thread r = gate row r).
__global__ __launch_bounds__(1024) void lstm_kernel(
    const int* __restrict__ data, const float* __restrict__ emb,
    const __hip_bfloat16* __restrict__ wbf, const float* __restrict__ biasb,
    __hip_bfloat16* __restrict__ hf, __hip_bfloat16* __restrict__ hb){
  const int chunk = blockIdx.x;
  const int dir   = blockIdx.y;
  const int r = threadIdx.x;
  const int b0 = chunk*2;
  __shared__ __align__(16) float xs[2][ED];
  __shared__ __align__(16) float hsm[2][HD];
  __shared__ __align__(16) float gsm[2][GG];
  const uint4* wih4 = (const uint4*)(wbf + (size_t)dir*393216 + (size_t)r*ED);
  const uint4* whh4 = (const uint4*)(wbf + (size_t)dir*393216 + 131072 + (size_t)r*HD);
  const float biasr = biasb[dir*GG + r];
  __hip_bfloat16* hout = dir ? hb : hf;
  if (r < 2*HD) ((float*)hsm)[r] = 0.f;
  float creg = 0.f;
  const int j = r >> 8;   // valid for r < 512
  const int u = r & 255;
  for (int t=0; t<SL; ++t){
    const int tt = dir ? (SL-1-t) : t;
    if (r < 2*ED){
      int jj = r >> 7, k = r & 127;
      int idx = data[(b0+jj)*SL + tt];
      xs[jj][k] = emb[(size_t)idx*ED + k];
    }
    __syncthreads();   // xs ready; hsm from previous update ready
    float a0 = biasr, a1 = biasr;
    {
      const float4* x0 = (const float4*)xs[0];
      const float4* x1 = (const float4*)xs[1];
      #pragma unroll
      for (int c=0;c<16;++c){
        uint4 wv = wih4[c]; float w8[8]; unpack8(wv, w8);
        float4 pa = x0[2*c], pb = x0[2*c+1];
        a0 += w8[0]*pa.x + w8[1]*pa.y + w8[2]*pa.z + w8[3]*pa.w
            + w8[4]*pb.x + w8[5]*pb.y + w8[6]*pb.z + w8[7]*pb.w;
        float4 qa = x1[2*c], qb = x1[2*c+1];
        a1 += w8[0]*qa.x + w8[1]*qa.y + w8[2]*qa.z + w8[3]*qa.w
            + w8[4]*qb.x + w8[5]*qb.y + w8[6]*qb.z + w8[7]*qb.w;
      }
      const float4* h0 = (const float4*)hsm[0];
      const float4* h1 = (const float4*)hsm[1];
      #pragma unroll
      for (int c=0;c<32;++c){
        uint4 wv = whh4[c]; float w8[8]; unpack8(wv, w8);
        float4 pa = h0[2*c], pb = h0[2*c+1];
        a0 += w8[0]*pa.x + w8[1]*pa.y + w8[2]*pa.z + w8[3]*pa.w
            + w8[4]*pb.x + w8[5]*pb.y + w8[6]*pb.z + w8[7]*pb.w;
        float4 qa = h1[2*c], qb = h1[2*c+1];
        a1 += w8[0]*qa.x + w8[1]*qa.y + w8[2]*qa.z + w8[3]*qa.w
            + w8[4]*qb.x + w8[5]*qb.y + w8[6]*qb.z + w8[7]*qb.w;
      }
    }
    gsm[0][r] = a0; gsm[1][r] = a1;
    __syncthreads();   // g ready
    if (r < 2*HD){
      float gi = gsm[j][u], gf = gsm[j][u+256], gc = gsm[j][u+512], go = gsm[j][u+768];
      float cn = sigf(gf)*creg + sigf(gi)*tanhf(gc);
      creg = cn;
      float hh = sigf(go)*tanhf(cn);
      hsm[j][u] = hh;
      hout[((size_t)(b0+j)*SL + tt)*HD + u] = __float2bfloat16(hh);
    }
    // next iteration's first barrier orders hsm write -> dot reads,
    // and gsm reads (here) -> next gsm writes (after that barrier).
  }
}

// K2: emission = concat(hf,hb) @ cls_w^T + cls_b. Thread per (row,tag).
__global__ void emis_kernel(const __hip_bfloat16* __restrict__ hf,
                            const __hip_bfloat16* __restrict__ hb,
                            const float* __restrict__ clsw, const float* __restrict__ clsb,
                            float* __restrict__ emis){
  int i = blockIdx.x*blockDim.x + threadIdx.x;
  if (i >= NB*SL*NT) return;
  int row = i / NT;
  int tag = i - row*NT;
  const uint4*  h4a = (const uint4*)(hf + (size_t)row*HD);
  const uint4*  h4b = (const uint4*)(hb + (size_t)row*HD);
  const float4* w4  = (const float4*)(clsw + (size_t)tag*512);
  float acc = clsb[tag];
  #pragma unroll
  for (int c=0;c<32;++c){
    uint4 hv = h4a[c]; float h8[8]; unpack8(hv, h8);
    float4 wa = w4[2*c], wb = w4[2*c+1];
    acc += h8[0]*wa.x + h8[1]*wa.y + h8[2]*wa.z + h8[3]*wa.w
         + h8[4]*wb.x + h8[5]*wb.y + h8[6]*wb.z + h8[7]*wb.w;
  }
  #pragma unroll
  for (int c=0;c<32;++c){
    uint4 hv = h4b[c]; float h8[8]; unpack8(hv, h8);
    float4 wa = w4[64+2*c], wb = w4[64+2*c+1];
    acc += h8[0]*wa.x + h8[1]*wa.y + h8[2]*wa.z + h8[3]*wa.w
         + h8[4]*wb.x + h8[5]*wb.y + h8[6]*wb.z + h8[7]*wb.w;
  }
  emis[i] = acc;
}

// K3: gold score + CRF forward (linear-space with per-step rescale).
// One block (64 threads = 1 wave) per batch element.
__global__ void crf_kernel(const float* __restrict__ emis, const float* __restrict__ trans,
                           const int* __restrict__ tags, float* __restrict__ diff){
  const int b = blockIdx.x, l = threadIdx.x;
  __shared__ float Elds[NT*NT];
  __shared__ float aL[NT];
  // gold score
  float gp = 0.f;
  for (int t=l; t<SL; t+=64){
    int tg = tags[b*SL+t];
    int pv = (t>0) ? tags[b*SL+t-1] : TSTART;
    gp += emis[((size_t)(b*SL)+t)*NT + tg] + trans[tg*NT+pv];
  }
  #pragma unroll
  for (int m=1;m<64;m<<=1) gp += __shfl_xor(gp, m);
  // E = exp(transition); exp(-10000)=0 matches reference underflow
  for (int i=l; i<NT*NT; i+=64) Elds[i] = expf(trans[i]);
  if (l < NT) aL[l] = (l==TSTART) ? 1.f : 0.f;
  __syncthreads();
  float logZ = 0.f;
  for (int t=0; t<SL; ++t){
    float v = 0.f;
    if (l < NT){
      float s = 0.f;
      #pragma unroll
      for (int p=0;p<NT;++p) s += Elds[l*NT+p]*aL[p];
      v = s * expf(emis[((size_t)(b*SL)+t)*NT + l]);
    }
    float tot = v;
    #pragma unroll
    for (int m=1;m<64;m<<=1) tot += __shfl_xor(tot, m);
    logZ += logf(tot);
    __syncthreads();
    if (l < NT) aL[l] = v/tot;
    __syncthreads();
  }
  if (l == 0) diff[b] = logZ - gp;   // fwd - gold
}

// K4: loss = mean(diff)
__global__ void final_kernel(const float* __restrict__ diff, float* __restrict__ out){
  int l = threadIdx.x;
  float v = diff[l];
  #pragma unroll
  for (int m=1;m<64;m<<=1) v += __shfl_xor(v, m);
  if (l == 0) out[0] = v * (1.f/64.f);
}

extern "C" void kernel_launch(void* const* d_in, const int* in_sizes, int n_in,
                              void* d_out, int out_size, void* d_ws, size_t ws_size,
                              hipStream_t stream){
  const int*   data = (const int*)d_in[0];
  const int*   tags = (const int*)d_in[2];
  const float* emb  = (const float*)d_in[3];
  const float* wihf = (const float*)d_in[4];
  const float* whhf = (const float*)d_in[5];
  const float* bihf = (const float*)d_in[6];
  const float* bhhf = (const float*)d_in[7];
  const float* wihb = (const float*)d_in[8];
  const float* whhb = (const float*)d_in[9];
  const float* bihb = (const float*)d_in[10];
  const float* bhhb = (const float*)d_in[11];
  const float* clsw = (const float*)d_in[12];
  const float* clsb = (const float*)d_in[13];
  const float* trans= (const float*)d_in[14];

  char* ws = (char*)d_ws;
  __hip_bfloat16* hf  = (__hip_bfloat16*)(ws);                 // 33,554,432 B
  __hip_bfloat16* hb  = (__hip_bfloat16*)(ws + 33554432);      // 33,554,432 B
  float*          emis= (float*)(ws + 67108864);               //  9,175,040 B
  __hip_bfloat16* wbf = (__hip_bfloat16*)(ws + 76283904);      //  1,572,864 B
  float*          bias= (float*)(ws + 77856768);               //      8,192 B
  float*          diff= (float*)(ws + 77864960);               //        256 B
  float* out = (float*)d_out;

  conv_kernel<<<dim3(3072), dim3(256), 0, stream>>>(
      wihf, whhf, wihb, whhb, bihf, bhhf, bihb, bhhb, wbf, bias);
  lstm_kernel<<<dim3(32,2), dim3(1024), 0, stream>>>(
      data, emb, wbf, bias, hf, hb);
  int total = NB*SL*NT;
  emis_kernel<<<dim3((total+255)/256), dim3(256), 0, stream>>>(
      hf, hb, clsw, clsb, emis);
  crf_kernel<<<dim3(64), dim3(64), 0, stream>>>(emis, trans, tags, diff);
  final_kernel<<<dim3(1), dim3(64), 0, stream>>>(diff, out);
}

// Round 2
// 5795.812 us; speedup vs baseline: 3.8678x; 3.8678x over previous
//
#include <hip/hip_runtime.h>
#include <hip/hip_bf16.h>
#include <cstdint>

#define NB 64      // batch
#define SL 1024    // seq len
#define ED 128     // embed
#define HD 256     // hidden
#define NT 35      // tags
#define TSTART 33

typedef unsigned int uint;
typedef __attribute__((ext_vector_type(8))) short short8;
typedef __attribute__((ext_vector_type(4))) float floatx4;

#define EXHALF 16384   // dwords per slot: 2dir*4bg*16b*128dw
#define NCLUST 8       // blocks per cluster

__device__ __forceinline__ float sigf(float x){ return 1.f/(1.f+expf(-x)); }

__device__ __forceinline__ unsigned short f2bf(float f){
  __hip_bfloat16 b = __float2bfloat16(f);
  return __builtin_bit_cast(unsigned short, b);
}
__device__ __forceinline__ uint pk2(float a, float b){
  return (uint)f2bf(a) | ((uint)f2bf(b)<<16);
}

__device__ __forceinline__ void unpack8(uint4 w, float* f){
  f[0]=__uint_as_float(w.x<<16); f[1]=__uint_as_float(w.x&0xffff0000u);
  f[2]=__uint_as_float(w.y<<16); f[3]=__uint_as_float(w.y&0xffff0000u);
  f[4]=__uint_as_float(w.z<<16); f[5]=__uint_as_float(w.z&0xffff0000u);
  f[6]=__uint_as_float(w.w<<16); f[7]=__uint_as_float(w.w&0xffff0000u);
}

// K-1: zero exchange buffer + cluster counters (re-run every launch).
__global__ void zero_kernel(uint* __restrict__ exch, uint* __restrict__ ctr){
  int i = blockIdx.x*blockDim.x + threadIdx.x;
  if (i < 2*EXHALF) exch[i] = 0u;
  if (i < 256) ctr[i] = 0u;
}

// K1: persistent clustered BiLSTM.
// grid 64 blocks x 256 threads. block = (dir, batch-group of 16, unit-slice of 32).
// Weights live in VGPRs as MFMA B-fragments (loaded once). Per step:
// stage x(t)+h(t-1) into swizzled LDS -> 24 MFMA/wave -> gate combine via LDS
// -> c/h update -> h exchange via agent atomics + cluster counter barrier.
__global__ __launch_bounds__(256, 1) void lstm_cluster(
    const int* __restrict__ data, const float* __restrict__ emb,
    const float* __restrict__ wihf, const float* __restrict__ whhf,
    const float* __restrict__ bihf, const float* __restrict__ bhhf,
    const float* __restrict__ wihb, const float* __restrict__ whhb,
    const float* __restrict__ bihb, const float* __restrict__ bhhb,
    uint* __restrict__ exch, uint* __restrict__ ctr,
    uint* __restrict__ hf, uint* __restrict__ hb){
  const int tid  = threadIdx.x;
  const int lane = tid & 63;
  const int w    = tid >> 6;            // wave id == gate id (i,f,g,o)
  const int dir  = blockIdx.x >> 5;
  const int bg   = (blockIdx.x >> 3) & 3;
  const int kblk = blockIdx.x & 7;      // unit-slice: units [32*kblk, 32*kblk+32)
  const int cl   = blockIdx.x >> 3;     // cluster id (0..7)

  __shared__ __align__(16) unsigned short xh[16*384]; // [b][k] bf16, XOR-swizzled
  __shared__ float gsm[128*17];                       // [row][batch] padded

  const float* Wih = dir ? wihb : wihf;   // [1024][128]
  const float* Whh = dir ? whhb : whhf;   // [1024][256]
  const float* Bih = dir ? bihb : bihf;
  const float* Bhh = dir ? bhhb : bhhf;

  // ---- one-time: load weight B-fragments into registers ----
  short8 bfrag[2][12];
  float bias2[2];
  const int koff = (lane>>4)*8;
  #pragma unroll
  for (int tau=0; tau<2; ++tau){
    int ul = tau*16 + (lane&15);
    int R  = w*256 + kblk*32 + ul;      // global gate row
    bias2[tau] = Bih[R] + Bhh[R];
    #pragma unroll
    for (int s=0; s<12; ++s){
      const float* src = (s<4) ? (Wih + (size_t)R*ED + s*32 + koff)
                               : (Whh + (size_t)R*HD + (s-4)*32 + koff);
      float4 f0 = ((const float4*)src)[0];
      float4 f1 = ((const float4*)src)[1];
      short8 v;
      v[0]=(short)f2bf(f0.x); v[1]=(short)f2bf(f0.y);
      v[2]=(short)f2bf(f0.z); v[3]=(short)f2bf(f0.w);
      v[4]=(short)f2bf(f1.x); v[5]=(short)f2bf(f1.y);
      v[6]=(short)f2bf(f1.z); v[7]=(short)f2bf(f1.w);
      bfrag[tau][s] = v;
    }
  }

  // staging role: thread -> (batch sb, chunk sc)
  const int sb = tid >> 4;
  const int sc = tid & 15;
  // update role: thread -> (batch ub, unit-pair up)
  const int ub = tid >> 4;
  const int up = tid & 15;
  // A-fragment addressing
  const int arow  = lane & 15;
  const int abase = arow*768 + (lane>>4)*16;
  const int aswz  = (arow & 7) << 4;
  char* xhb = (char*)xh;

  uint* hout = dir ? hb : hf;
  uint* myctr = ctr + cl*32;

  float creg0 = 0.f, creg1 = 0.f;

  for (int t=0; t<SL; ++t){
    const int tt = dir ? (SL-1-t) : t;
    const int slot_r = (t+1) & 1;   // t=0 reads slot 1 (zeroed)
    const int slot_w = t & 1;

    // ---- stage x(t): emb gather -> bf16 -> LDS (swizzled) ----
    {
      int token = data[(bg*16+sb)*SL + tt];
      const float4* ep = (const float4*)(emb + (size_t)token*ED + sc*8);
      float4 e0 = ep[0], e1 = ep[1];
      uint4 xv;
      xv.x = pk2(e0.x, e0.y); xv.y = pk2(e0.z, e0.w);
      xv.z = pk2(e1.x, e1.y); xv.w = pk2(e1.z, e1.w);
      int off = (sb*768 + sc*16) ^ ((sb&7)<<4);
      *(uint4*)(xhb + off) = xv;
    }
    // ---- stage h(t-1): agent-atomic loads from exchange -> LDS ----
    {
      const uint* exr = exch + slot_r*EXHALF + ((size_t)((dir*4+bg)*16 + sb))*128 + sc*8;
      uint hv[8];
      #pragma unroll
      for (int j=0;j<8;++j)
        hv[j] = __hip_atomic_load(exr+j, __ATOMIC_RELAXED, __HIP_MEMORY_SCOPE_AGENT);
      uint4 h0; h0.x=hv[0]; h0.y=hv[1]; h0.z=hv[2]; h0.w=hv[3];
      uint4 h1; h1.x=hv[4]; h1.y=hv[5]; h1.z=hv[6]; h1.w=hv[7];
      int off0 = (sb*768 + 256 + sc*32) ^ ((sb&7)<<4);
      int off1 = (sb*768 + 256 + sc*32 + 16) ^ ((sb&7)<<4);
      *(uint4*)(xhb + off0) = h0;
      *(uint4*)(xhb + off1) = h1;
    }
    __syncthreads();

    // ---- MFMA: gates[16 batch][32 rows of this wave] ----
    floatx4 acc0; acc0[0]=bias2[0]; acc0[1]=bias2[0]; acc0[2]=bias2[0]; acc0[3]=bias2[0];
    floatx4 acc1; acc1[0]=bias2[1]; acc1[1]=bias2[1]; acc1[2]=bias2[1]; acc1[3]=bias2[1];
    #pragma unroll
    for (int s=0; s<12; ++s){
      short8 afrag = *(const short8*)(xhb + ((abase + s*64) ^ aswz));
      acc0 = __builtin_amdgcn_mfma_f32_16x16x32_bf16(afrag, bfrag[0][s], acc0, 0,0,0);
      acc1 = __builtin_amdgcn_mfma_f32_16x16x32_bf16(afrag, bfrag[1][s], acc1, 0,0,0);
    }
    // write gates to LDS: gsm[row_local][batch]
    {
      int gn = w*32 + (lane&15);
      int gm = (lane>>4)*4;
      #pragma unroll
      for (int j=0;j<4;++j){
        gsm[(gn   )*17 + gm + j] = acc0[j];
        gsm[(gn+16)*17 + gm + j] = acc1[j];
      }
    }
    __syncthreads();

    // ---- c/h update for 2 units (u=2up, 2up+1), batch ub ----
    {
      int u0 = 2*up, u1 = 2*up+1;
      float gi0 = gsm[(0*32+u0)*17+ub], gf0 = gsm[(1*32+u0)*17+ub];
      float gg0 = gsm[(2*32+u0)*17+ub], go0 = gsm[(3*32+u0)*17+ub];
      float gi1 = gsm[(0*32+u1)*17+ub], gf1 = gsm[(1*32+u1)*17+ub];
      float gg1 = gsm[(2*32+u1)*17+ub], go1 = gsm[(3*32+u1)*17+ub];
      float c0 = sigf(gf0)*creg0 + sigf(gi0)*tanhf(gg0); creg0 = c0;
      float c1 = sigf(gf1)*creg1 + sigf(gi1)*tanhf(gg1); creg1 = c1;
      float h0 = sigf(go0)*tanhf(c0);
      float h1 = sigf(go1)*tanhf(c1);
      uint hpack = pk2(h0, h1);
      uint* exw = exch + slot_w*EXHALF + ((size_t)((dir*4+bg)*16 + ub))*128 + kblk*16 + up;
      __hip_atomic_store(exw, hpack, __ATOMIC_RELAXED, __HIP_MEMORY_SCOPE_AGENT);
      hout[((size_t)(bg*16+ub)*SL + tt)*128 + kblk*16 + up] = hpack;
    }
    __syncthreads();   // drains the atomic stores (vmcnt) before the counter add

    // ---- cluster barrier ----
    if (tid == 0){
      __hip_atomic_fetch_add(myctr, 1u, __ATOMIC_RELEASE, __HIP_MEMORY_SCOPE_AGENT);
      uint target = (uint)(NCLUST*(t+1));
      while (__hip_atomic_load(myctr, __ATOMIC_ACQUIRE, __HIP_MEMORY_SCOPE_AGENT) < target) {}
    }
    __syncthreads();
  }
}

// K2: emission = concat(hf,hb) @ cls_w^T + cls_b. Thread per (row,tag).
__global__ void emis_kernel(const __hip_bfloat16* __restrict__ hf,
                            const __hip_bfloat16* __restrict__ hb,
                            const float* __restrict__ clsw, const float* __restrict__ clsb,
                            float* __restrict__ emis){
  int i = blockIdx.x*blockDim.x + threadIdx.x;
  if (i >= NB*SL*NT) return;
  int row = i / NT;
  int tag = i - row*NT;
  const uint4*  h4a = (const uint4*)(hf + (size_t)row*HD);
  const uint4*  h4b = (const uint4*)(hb + (size_t)row*HD);
  const float4* w4  = (const float4*)(clsw + (size_t)tag*512);
  float acc = clsb[tag];
  #pragma unroll
  for (int c=0;c<32;++c){
    uint4 hv = h4a[c]; float h8[8]; unpack8(hv, h8);
    float4 wa = w4[2*c], wb = w4[2*c+1];
    acc += h8[0]*wa.x + h8[1]*wa.y + h8[2]*wa.z + h8[3]*wa.w
         + h8[4]*wb.x + h8[5]*wb.y + h8[6]*wb.z + h8[7]*wb.w;
  }
  #pragma unroll
  for (int c=0;c<32;++c){
    uint4 hv = h4b[c]; float h8[8]; unpack8(hv, h8);
    float4 wa = w4[64+2*c], wb = w4[64+2*c+1];
    acc += h8[0]*wa.x + h8[1]*wa.y + h8[2]*wa.z + h8[3]*wa.w
         + h8[4]*wb.x + h8[5]*wb.y + h8[6]*wb.z + h8[7]*wb.w;
  }
  emis[i] = acc;
}

// K3: gold score + CRF forward (linear-space with per-step rescale).
__global__ void crf_kernel(const float* __restrict__ emis, const float* __restrict__ trans,
                           const int* __restrict__ tags, float* __restrict__ diff){
  const int b = blockIdx.x, l = threadIdx.x;
  __shared__ float Elds[NT*NT];
  __shared__ float aL[NT];
  float gp = 0.f;
  for (int t=l; t<SL; t+=64){
    int tg = tags[b*SL+t];
    int pv = (t>0) ? tags[b*SL+t-1] : TSTART;
    gp += emis[((size_t)(b*SL)+t)*NT + tg] + trans[tg*NT+pv];
  }
  #pragma unroll
  for (int m=1;m<64;m<<=1) gp += __shfl_xor(gp, m);
  for (int i=l; i<NT*NT; i+=64) Elds[i] = expf(trans[i]);
  if (l < NT) aL[l] = (l==TSTART) ? 1.f : 0.f;
  __syncthreads();
  float logZ = 0.f;
  for (int t=0; t<SL; ++t){
    float v = 0.f;
    if (l < NT){
      float s = 0.f;
      #pragma unroll
      for (int p=0;p<NT;++p) s += Elds[l*NT+p]*aL[p];
      v = s * expf(emis[((size_t)(b*SL)+t)*NT + l]);
    }
    float tot = v;
    #pragma unroll
    for (int m=1;m<64;m<<=1) tot += __shfl_xor(tot, m);
    logZ += logf(tot);
    __syncthreads();
    if (l < NT) aL[l] = v/tot;
    __syncthreads();
  }
  if (l == 0) diff[b] = logZ - gp;
}

// K4: loss = mean(diff)
__global__ void final_kernel(const float* __restrict__ diff, float* __restrict__ out){
  int l = threadIdx.x;
  float v = diff[l];
  #pragma unroll
  for (int m=1;m<64;m<<=1) v += __shfl_xor(v, m);
  if (l == 0) out[0] = v * (1.f/64.f);
}

extern "C" void kernel_launch(void* const* d_in, const int* in_sizes, int n_in,
                              void* d_out, int out_size, void* d_ws, size_t ws_size,
                              hipStream_t stream){
  const int*   data = (const int*)d_in[0];
  const int*   tags = (const int*)d_in[2];
  const float* emb  = (const float*)d_in[3];
  const float* wihf = (const float*)d_in[4];
  const float* whhf = (const float*)d_in[5];
  const float* bihf = (const float*)d_in[6];
  const float* bhhf = (const float*)d_in[7];
  const float* wihb = (const float*)d_in[8];
  const float* whhb = (const float*)d_in[9];
  const float* bihb = (const float*)d_in[10];
  const float* bhhb = (const float*)d_in[11];
  const float* clsw = (const float*)d_in[12];
  const float* clsb = (const float*)d_in[13];
  const float* trans= (const float*)d_in[14];

  char* ws = (char*)d_ws;
  uint*  hf   = (uint*)(ws);                    // 33,554,432 B (bf16 [B][L][256])
  uint*  hb   = (uint*)(ws + 33554432);         // 33,554,432 B
  float* emis = (float*)(ws + 67108864);        //  9,175,040 B
  uint*  exch = (uint*)(ws + 76283904);         //    131,072 B
  uint*  ctr  = (uint*)(ws + 76414976);         //      1,024 B
  float* diff = (float*)(ws + 76416000);        //        256 B
  float* out  = (float*)d_out;

  zero_kernel<<<dim3(129), dim3(256), 0, stream>>>(exch, ctr);
  lstm_cluster<<<dim3(64), dim3(256), 0, stream>>>(
      data, emb, wihf, whhf, bihf, bhhf, wihb, whhb, bihb, bhhb,
      exch, ctr, hf, hb);
  int total = NB*SL*NT;
  emis_kernel<<<dim3((total+255)/256), dim3(256), 0, stream>>>(
      (const __hip_bfloat16*)hf, (const __hip_bfloat16*)hb, clsw, clsb, emis);
  crf_kernel<<<dim3(64), dim3(64), 0, stream>>>(emis, trans, tags, diff);
  final_kernel<<<dim3(1), dim3(64), 0, stream>>>(diff, out);
}

// Round 3
// 3605.139 us; speedup vs baseline: 6.2180x; 1.6077x over previous
//
#include <hip/hip_runtime.h>
#include <hip/hip_bf16.h>
#include <cstdint>

#define NB 64      // batch
#define SL 1024    // seq len
#define ED 128     // embed
#define HD 256     // hidden
#define NT 35      // tags
#define TSTART 33

typedef unsigned int uint;
typedef __attribute__((ext_vector_type(8))) short short8;
typedef __attribute__((ext_vector_type(4))) float floatx4;

#define EXHALF 16384   // dwords per slot: 2dir*4bg*16b*128dw

__device__ __forceinline__ float fsig(float x){
  // 1/(1+e^-x); e^-x=inf -> rcp(inf)=0: graceful
  return __builtin_amdgcn_rcpf(1.f + __expf(-x));
}
__device__ __forceinline__ float ftanh(float x){
  float ax = fabsf(x);
  float e  = __expf(2.f*ax);                       // inf ok
  float r  = 1.f - 2.f*__builtin_amdgcn_rcpf(e+1.f);
  return copysignf(r, x);
}

__device__ __forceinline__ unsigned short f2bf(float f){
  __hip_bfloat16 b = __float2bfloat16(f);
  return __builtin_bit_cast(unsigned short, b);
}
__device__ __forceinline__ uint pk2(float a, float b){
  return (uint)f2bf(a) | ((uint)f2bf(b)<<16);
}
__device__ __forceinline__ void unpack8(uint4 w, float* f){
  f[0]=__uint_as_float(w.x<<16); f[1]=__uint_as_float(w.x&0xffff0000u);
  f[2]=__uint_as_float(w.y<<16); f[3]=__uint_as_float(w.y&0xffff0000u);
  f[4]=__uint_as_float(w.z<<16); f[5]=__uint_as_float(w.z&0xffff0000u);
  f[6]=__uint_as_float(w.w<<16); f[7]=__uint_as_float(w.w&0xffff0000u);
}

// K-1: init exchange buffer to bit0=1 (tag mismatch vs first expected tag 0;
// also rejects the 0xAA poison whose bit0=0). Re-run every launch.
__global__ void zero_kernel(uint* __restrict__ exch){
  int i = blockIdx.x*blockDim.x + threadIdx.x;
  if (i < 2*EXHALF) exch[i] = 1u;
}

// K0: pre-gather x = bf16(emb[data]) : [B][L][128] bf16 (16 uint4 per row)
__global__ void xgather_kernel(const int* __restrict__ data, const float* __restrict__ emb,
                               uint4* __restrict__ xbf){
  int i = blockIdx.x*blockDim.x + threadIdx.x;   // NB*SL*16
  if (i >= NB*SL*16) return;
  int bt = i >> 4;
  int c  = i & 15;
  int token = data[bt];
  const float4* ep = (const float4*)(emb + (size_t)token*ED + c*8);
  float4 e0 = ep[0], e1 = ep[1];
  uint4 xv;
  xv.x = pk2(e0.x, e0.y); xv.y = pk2(e0.z, e0.w);
  xv.z = pk2(e1.x, e1.y); xv.w = pk2(e1.z, e1.w);
  xbf[(size_t)bt*16 + c] = xv;
}

// K1: persistent clustered BiLSTM, parity-tagged lock-free h exchange.
// grid 64 blocks x 256 threads: block = (dir, batch-group of 16, 32-unit slice).
// Sync protocol: h(t) stored in slot t&1 with bit0 tag (t>>1)&1 on every dword.
// Consumer at step t polls slot (t-1)&1 for tag ((t-1)>>1)&1 — data IS the flag.
// Safety: consuming h(t-1) precedes producing h(t) precedes anyone writing
// h(t+1), so a slot is never overwritten before all its readers are done, and
// the overwriting step's tag always differs from the awaited one.
__global__ __launch_bounds__(256, 1) void lstm_cluster(
    const uint4* __restrict__ xbf,
    const float* __restrict__ wihf, const float* __restrict__ whhf,
    const float* __restrict__ bihf, const float* __restrict__ bhhf,
    const float* __restrict__ wihb, const float* __restrict__ whhb,
    const float* __restrict__ bihb, const float* __restrict__ bhhb,
    uint* __restrict__ exch,
    uint* __restrict__ hf, uint* __restrict__ hb){
  const int tid  = threadIdx.x;
  const int lane = tid & 63;
  const int w    = tid >> 6;            // wave id == gate id (i,f,g,o)
  const int dir  = blockIdx.x >> 5;
  const int bg   = (blockIdx.x >> 3) & 3;
  const int kblk = blockIdx.x & 7;      // unit slice [32*kblk, 32*kblk+32)

  __shared__ __align__(16) unsigned short xh[16*384]; // [b][k] bf16, XOR-swizzled
  __shared__ float gsm[128*17];                       // [row][batch] padded

  const float* Wih = dir ? wihb : wihf;
  const float* Whh = dir ? whhb : whhf;
  const float* Bih = dir ? bihb : bihf;
  const float* Bhh = dir ? bhhb : bhhf;

  // ---- one-time: weight B-fragments into registers ----
  short8 bfrag[2][12];
  float bias2[2];
  const int koff = (lane>>4)*8;
  #pragma unroll
  for (int tau=0; tau<2; ++tau){
    int ul = tau*16 + (lane&15);
    int R  = w*256 + kblk*32 + ul;
    bias2[tau] = Bih[R] + Bhh[R];
    #pragma unroll
    for (int s=0; s<12; ++s){
      const float* src = (s<4) ? (Wih + (size_t)R*ED + s*32 + koff)
                               : (Whh + (size_t)R*HD + (s-4)*32 + koff);
      float4 f0 = ((const float4*)src)[0];
      float4 f1 = ((const float4*)src)[1];
      short8 v;
      v[0]=(short)f2bf(f0.x); v[1]=(short)f2bf(f0.y);
      v[2]=(short)f2bf(f0.z); v[3]=(short)f2bf(f0.w);
      v[4]=(short)f2bf(f1.x); v[5]=(short)f2bf(f1.y);
      v[6]=(short)f2bf(f1.z); v[7]=(short)f2bf(f1.w);
      bfrag[tau][s] = v;
    }
  }

  const int sb = tid >> 4;          // staging batch
  const int sc = tid & 15;          // staging chunk
  const int ub = tid >> 4;          // update batch
  const int up = tid & 15;          // update unit-pair
  const int arow  = lane & 15;
  const int abase = arow*768 + (lane>>4)*16;
  const int aswz  = (arow & 7) << 4;
  char* xhb = (char*)xh;

  uint* hout = dir ? hb : hf;
  const size_t exrd_base = (size_t)((dir*4+bg)*16 + sb)*128 + sc*8;
  const size_t exwr_base = (size_t)((dir*4+bg)*16 + ub)*128 + kblk*16 + up;
  const size_t xrow_base = (size_t)(bg*16+sb)*SL;

  float creg0 = 0.f, creg1 = 0.f;

  for (int t=0; t<SL; ++t){
    const int tt = dir ? (SL-1-t) : t;

    // ---- issue x load (independent of h) ----
    uint4 xv = xbf[(xrow_base + tt)*16 + sc];

    // ---- h(t-1): poll parity-tagged exchange ----
    uint hv[8];
    if (t == 0){
      #pragma unroll
      for (int j=0;j<8;++j) hv[j] = 0u;
    } else {
      const uint* exr = exch + (size_t)((t-1)&1)*EXHALF + exrd_base;
      const uint expect = ((uint)(t-1)>>1)&1u;
      for (;;){
        uint ok = 1u;
        #pragma unroll
        for (int j=0;j<8;++j)
          hv[j] = __hip_atomic_load(exr+j, __ATOMIC_RELAXED, __HIP_MEMORY_SCOPE_AGENT);
        #pragma unroll
        for (int j=0;j<8;++j) ok &= (uint)((hv[j]&1u)==expect);
        if (ok) break;
      }
      #pragma unroll
      for (int j=0;j<8;++j) hv[j] &= ~1u;   // strip tag
    }

    // ---- stage x + h into swizzled LDS ----
    *(uint4*)(xhb + ((sb*768 + sc*16) ^ ((sb&7)<<4))) = xv;
    uint4 h0; h0.x=hv[0]; h0.y=hv[1]; h0.z=hv[2]; h0.w=hv[3];
    uint4 h1; h1.x=hv[4]; h1.y=hv[5]; h1.z=hv[6]; h1.w=hv[7];
    *(uint4*)(xhb + ((sb*768 + 256 + sc*32)      ^ ((sb&7)<<4))) = h0;
    *(uint4*)(xhb + ((sb*768 + 256 + sc*32 + 16) ^ ((sb&7)<<4))) = h1;
    __syncthreads();   // staging done; also orders update(t-1) gsm reads before gsm writes below

    // ---- MFMA: gates[16 batch][32 rows of this wave] ----
    floatx4 acc0; acc0[0]=bias2[0]; acc0[1]=bias2[0]; acc0[2]=bias2[0]; acc0[3]=bias2[0];
    floatx4 acc1; acc1[0]=bias2[1]; acc1[1]=bias2[1]; acc1[2]=bias2[1]; acc1[3]=bias2[1];
    #pragma unroll
    for (int s=0; s<12; ++s){
      short8 afrag = *(const short8*)(xhb + ((abase + s*64) ^ aswz));
      acc0 = __builtin_amdgcn_mfma_f32_16x16x32_bf16(afrag, bfrag[0][s], acc0, 0,0,0);
      acc1 = __builtin_amdgcn_mfma_f32_16x16x32_bf16(afrag, bfrag[1][s], acc1, 0,0,0);
    }
    {
      int gn = w*32 + (lane&15);
      int gm = (lane>>4)*4;
      #pragma unroll
      for (int j=0;j<4;++j){
        gsm[(gn   )*17 + gm + j] = acc0[j];
        gsm[(gn+16)*17 + gm + j] = acc1[j];
      }
    }
    __syncthreads();   // gsm ready; also orders MFMA xh reads before next staging writes

    // ---- c/h update for units (2up, 2up+1), batch ub ----
    {
      int u0 = 2*up, u1 = 2*up+1;
      float gi0 = gsm[(0*32+u0)*17+ub], gf0 = gsm[(1*32+u0)*17+ub];
      float gg0 = gsm[(2*32+u0)*17+ub], go0 = gsm[(3*32+u0)*17+ub];
      float gi1 = gsm[(0*32+u1)*17+ub], gf1 = gsm[(1*32+u1)*17+ub];
      float gg1 = gsm[(2*32+u1)*17+ub], go1 = gsm[(3*32+u1)*17+ub];
      float c0 = fsig(gf0)*creg0 + fsig(gi0)*ftanh(gg0); creg0 = c0;
      float c1 = fsig(gf1)*creg1 + fsig(gi1)*ftanh(gg1); creg1 = c1;
      float h0f = fsig(go0)*ftanh(c0);
      float h1f = fsig(go1)*ftanh(c1);
      uint hpack = pk2(h0f, h1f);
      uint exv = (hpack & ~1u) | ((uint)(t>>1)&1u);   // parity tag in bit0
      uint* exw = exch + (size_t)(t&1)*EXHALF + exwr_base;
      __hip_atomic_store(exw, exv, __ATOMIC_RELAXED, __HIP_MEMORY_SCOPE_AGENT);
      hout[(xrow_base /*==(bg*16+ub)*SL*/ + tt)*128 + kblk*16 + up] = hpack;
    }
    // no end barrier: next sync1 orders gsm reads vs next gsm writes.
  }
}

// K2: emission = concat(hf,hb) @ cls_w^T + cls_b. Thread per (row,tag).
__global__ void emis_kernel(const __hip_bfloat16* __restrict__ hf,
                            const __hip_bfloat16* __restrict__ hb,
                            const float* __restrict__ clsw, const float* __restrict__ clsb,
                            float* __restrict__ emis){
  int i = blockIdx.x*blockDim.x + threadIdx.x;
  if (i >= NB*SL*NT) return;
  int row = i / NT;
  int tag = i - row*NT;
  const uint4*  h4a = (const uint4*)(hf + (size_t)row*HD);
  const uint4*  h4b = (const uint4*)(hb + (size_t)row*HD);
  const float4* w4  = (const float4*)(clsw + (size_t)tag*512);
  float acc = clsb[tag];
  #pragma unroll
  for (int c=0;c<32;++c){
    uint4 hv = h4a[c]; float h8[8]; unpack8(hv, h8);
    float4 wa = w4[2*c], wb = w4[2*c+1];
    acc += h8[0]*wa.x + h8[1]*wa.y + h8[2]*wa.z + h8[3]*wa.w
         + h8[4]*wb.x + h8[5]*wb.y + h8[6]*wb.z + h8[7]*wb.w;
  }
  #pragma unroll
  for (int c=0;c<32;++c){
    uint4 hv = h4b[c]; float h8[8]; unpack8(hv, h8);
    float4 wa = w4[64+2*c], wb = w4[64+2*c+1];
    acc += h8[0]*wa.x + h8[1]*wa.y + h8[2]*wa.z + h8[3]*wa.w
         + h8[4]*wb.x + h8[5]*wb.y + h8[6]*wb.z + h8[7]*wb.w;
  }
  emis[i] = acc;
}

// K3: gold score + CRF forward (linear-space with per-step rescale).
__global__ void crf_kernel(const float* __restrict__ emis, const float* __restrict__ trans,
                           const int* __restrict__ tags, float* __restrict__ diff){
  const int b = blockIdx.x, l = threadIdx.x;
  __shared__ float Elds[NT*NT];
  __shared__ float aL[NT];
  float gp = 0.f;
  for (int t=l; t<SL; t+=64){
    int tg = tags[b*SL+t];
    int pv = (t>0) ? tags[b*SL+t-1] : TSTART;
    gp += emis[((size_t)(b*SL)+t)*NT + tg] + trans[tg*NT+pv];
  }
  #pragma unroll
  for (int m=1;m<64;m<<=1) gp += __shfl_xor(gp, m);
  for (int i=l; i<NT*NT; i+=64) Elds[i] = __expf(trans[i]);
  if (l < NT) aL[l] = (l==TSTART) ? 1.f : 0.f;
  __syncthreads();
  float logZ = 0.f;
  for (int t=0; t<SL; ++t){
    float v = 0.f;
    if (l < NT){
      float s = 0.f;
      #pragma unroll
      for (int p=0;p<NT;++p) s += Elds[l*NT+p]*aL[p];
      v = s * __expf(emis[((size_t)(b*SL)+t)*NT + l]);
    }
    float tot = v;
    #pragma unroll
    for (int m=1;m<64;m<<=1) tot += __shfl_xor(tot, m);
    logZ += __logf(tot);
    __syncthreads();
    if (l < NT) aL[l] = v/tot;
    __syncthreads();
  }
  if (l == 0) diff[b] = logZ - gp;
}

// K4: loss = mean(diff)
__global__ void final_kernel(const float* __restrict__ diff, float* __restrict__ out){
  int l = threadIdx.x;
  float v = diff[l];
  #pragma unroll
  for (int m=1;m<64;m<<=1) v += __shfl_xor(v, m);
  if (l == 0) out[0] = v * (1.f/64.f);
}

extern "C" void kernel_launch(void* const* d_in, const int* in_sizes, int n_in,
                              void* d_out, int out_size, void* d_ws, size_t ws_size,
                              hipStream_t stream){
  const int*   data = (const int*)d_in[0];
  const int*   tags = (const int*)d_in[2];
  const float* emb  = (const float*)d_in[3];
  const float* wihf = (const float*)d_in[4];
  const float* whhf = (const float*)d_in[5];
  const float* bihf = (const float*)d_in[6];
  const float* bhhf = (const float*)d_in[7];
  const float* wihb = (const float*)d_in[8];
  const float* whhb = (const float*)d_in[9];
  const float* bihb = (const float*)d_in[10];
  const float* bhhb = (const float*)d_in[11];
  const float* clsw = (const float*)d_in[12];
  const float* clsb = (const float*)d_in[13];
  const float* trans= (const float*)d_in[14];

  char* ws = (char*)d_ws;
  uint*  hf   = (uint*)(ws);                    // 33,554,432 B (bf16 [B][L][256])
  uint*  hb   = (uint*)(ws + 33554432);         // 33,554,432 B
  uint4* xbf  = (uint4*)(ws + 67108864);        // 16,777,216 B (bf16 x, lstm-only)
  float* emis = (float*)(ws + 67108864);        //  9,175,040 B (overlays xbf, post-lstm)
  uint*  exch = (uint*)(ws + 83886080);         //    131,072 B
  float* diff = (float*)(ws + 84017152);        //        256 B
  float* out  = (float*)d_out;

  zero_kernel<<<dim3(128), dim3(256), 0, stream>>>(exch);
  xgather_kernel<<<dim3(4096), dim3(256), 0, stream>>>(data, emb, xbf);
  lstm_cluster<<<dim3(64), dim3(256), 0, stream>>>(
      xbf, wihf, whhf, bihf, bhhf, wihb, whhb, bihb, bhhb,
      exch, hf, hb);
  int total = NB*SL*NT;
  emis_kernel<<<dim3((total+255)/256), dim3(256), 0, stream>>>(
      (const __hip_bfloat16*)hf, (const __hip_bfloat16*)hb, clsw, clsb, emis);
  crf_kernel<<<dim3(64), dim3(64), 0, stream>>>(emis, trans, tags, diff);
  final_kernel<<<dim3(1), dim3(64), 0, stream>>>(diff, out);
}